// Round 13
// baseline (333.927 us; speedup 1.0000x reference)
//
#include <hip/hip_runtime.h>
#include <math.h>

#define N_NODES 50000
#define N_EDGES 800000
#define ET (N_EDGES + N_NODES)   /* 850000 edges incl. self-loops */
#define F_IN 512
#define HID 64
#define HEADS 4
#define C1 (HEADS * HID)         /* 256 */
#define NCLS 40
#define NEG_SLOPE 0.2f

/* bucketed scatter params */
#define BUK_SHIFT 7
#define BUK_NODES (1 << BUK_SHIFT)                       /* 128 nodes per bucket */
#define NBUK ((N_NODES + BUK_NODES - 1) / BUK_NODES)    /* 391 */
#define CAP 4096           /* staging slots per bucket (mean load 2176) */
#define NREP 4             /* replicated append counters per bucket */
#define SUBCAP (CAP / NREP)  /* 1024 per sub-region (load ~544 +- 23) */
#define BF_STRIDE 8        /* ints between counters (32B) */
#define EPB_A 2048         /* edges per passA block */
#define NBLK_A ((ET + EPB_A - 1) / EPB_A)   /* 416 */
#define NG1 ((N_NODES + 127) / 128)         /* 391 gemm1 blocks */
#define RCAP 2560          /* place LDS record capacity (bucket mean 2176, +8 sigma) */

typedef __attribute__((ext_vector_type(8))) short short8;
typedef __attribute__((ext_vector_type(4))) float floatx4;

__device__ __forceinline__ float leaky(float x) { return fmaxf(x, NEG_SLOPE * x); }

// f32 -> bf16 round-to-nearest-even
__device__ __forceinline__ unsigned short f2bf(float f) {
    unsigned u = __float_as_uint(f);
    u += 0x7fffu + ((u >> 16) & 1u);
    return (unsigned short)(u >> 16);
}
__device__ __forceinline__ float bf2f(unsigned short u) {
    return __uint_as_float(((unsigned)u) << 16);
}
__device__ __forceinline__ float bflo(unsigned v) { return __uint_as_float(v << 16); }
__device__ __forceinline__ float bfhi(unsigned v) { return __uint_as_float(v & 0xffff0000u); }

__device__ __forceinline__ void edge_sd(int e, const int* __restrict__ ei,
                                        const float* __restrict__ ew,
                                        int& s, int& d, float& w) {
    if (e < N_EDGES) { s = ei[e]; d = ei[N_EDGES + e]; w = ew[e]; }
    else             { s = d = e - N_EDGES; w = 1.f; }
}

// ============ W1 -> bf16 transpose: WT[n][k] = bf16(W1[k][n]).
//              Block (0,0) also zeroes bfill (replaces hipMemsetAsync). ============
__global__ void wt_prep_kernel(const float* __restrict__ W, unsigned short* __restrict__ WT,
                               int* __restrict__ bfill) {
    __shared__ float tile[32][33];
    int k0 = blockIdx.x * 32;
    int n0 = blockIdx.y * 32;
    int tx = threadIdx.x, ty = threadIdx.y;    // 32 x 8
    if (blockIdx.x == 0 && blockIdx.y == 0) {
        int tid = ty * 32 + tx;
        for (int i = tid; i < NBUK * NREP * BF_STRIDE; i += 256) bfill[i] = 0;
    }
    #pragma unroll
    for (int i = 0; i < 32; i += 8)
        tile[ty + i][tx] = W[(size_t)(k0 + ty + i) * C1 + n0 + tx];
    __syncthreads();
    #pragma unroll
    for (int i = 0; i < 32; i += 8)
        WT[(size_t)(n0 + ty + i) * F_IN + k0 + tx] = f2bf(tile[tx][ty + i]);
}

// ====== FUSED: gemm1 (blocks 0..NG1-1, R5-proven structure) ||
//        passA bucket multisplit (blocks NG1..). [R9/R10-verified] ======
__global__ __launch_bounds__(512) void g1pa_kernel(const float* __restrict__ X,
                                                   const unsigned short* __restrict__ WT,
                                                   const float* __restrict__ a_s1,
                                                   const float* __restrict__ a_d1,
                                                   unsigned short* __restrict__ H,
                                                   float* __restrict__ AS,
                                                   float* __restrict__ AD,
                                                   const int* __restrict__ ei,
                                                   const float* __restrict__ ew,
                                                   int* __restrict__ bfill,
                                                   int2* __restrict__ SB) {
    __shared__ short As[128][40];
    __shared__ short Bs[256][40];
    __shared__ int lcnt[NBUK];
    __shared__ int lbase[NBUK];
    const int t = threadIdx.x;

    if (blockIdx.x >= NG1) {
        // ---------------- passA path (512 threads, 2048 edges) ----------------
        const int pb = blockIdx.x - NG1;
        const int rep = pb & (NREP - 1);
        const int e0 = pb * EPB_A + t;
        for (int i = t; i < NBUK; i += 512) lcnt[i] = 0;
        __syncthreads();
        int rx[4], ry[4];
        #pragma unroll
        for (int i = 0; i < 4; i++) {
            int e = e0 + i * 512;
            rx[i] = -1;                   /* d<=49999 -> packed word never -1 */
            ry[i] = 0;
            if (e < ET) {
                int s, d; float w;
                edge_sd(e, ei, ew, s, d, w);
                rx[i] = s | (d << 16);
                ry[i] = __float_as_int(w);
                atomicAdd(&lcnt[d >> BUK_SHIFT], 1);
            }
        }
        __syncthreads();
        for (int i = t; i < NBUK; i += 512) {
            int c = lcnt[i];
            lbase[i] = c ? atomicAdd(&bfill[(i * NREP + rep) * BF_STRIDE], c) : 0;
            lcnt[i] = 0;
        }
        __syncthreads();
        #pragma unroll
        for (int i = 0; i < 4; i++) {
            if (rx[i] != -1) {
                int b = ((unsigned)rx[i] >> 16) >> BUK_SHIFT;
                int r = atomicAdd(&lcnt[b], 1);
                int idx = lbase[b] + r;
                if (idx < SUBCAP)   /* hard bound: never fault */
                    SB[(size_t)b * CAP + rep * SUBCAP + idx] = make_int2(rx[i], ry[i]);
            }
        }
        return;
    }

    // ---------------- gemm1 path (R5-proven 512-thread structure) ----------------
    const int m0 = blockIdx.x * 128;
    const int lane = t & 63;
    const int wave = t >> 6;
    const int wm = wave >> 2;
    const int wn = wave & 3;
    const int l15 = lane & 15;
    const int quad = lane >> 4;

    const int ar = t >> 2;
    const int ac0 = (t & 3) * 8;
    const int gr = m0 + ar;
    const int bn = t >> 1;
    const int bc0 = (t & 1) * 16;

    floatx4 acc[4][4];
    #pragma unroll
    for (int i = 0; i < 4; i++)
        #pragma unroll
        for (int j = 0; j < 4; j++) acc[i][j] = (floatx4){0.f, 0.f, 0.f, 0.f};

    for (int k0 = 0; k0 < F_IN; k0 += 32) {
        float xv[8];
        if (gr < N_NODES) {
            const float4* p = (const float4*)(X + (size_t)gr * F_IN + k0 + ac0);
            float4 v0 = p[0], v1 = p[1];
            xv[0] = v0.x; xv[1] = v0.y; xv[2] = v0.z; xv[3] = v0.w;
            xv[4] = v1.x; xv[5] = v1.y; xv[6] = v1.z; xv[7] = v1.w;
        } else {
            #pragma unroll
            for (int i = 0; i < 8; i++) xv[i] = 0.f;
        }
        short8 av;
        #pragma unroll
        for (int i = 0; i < 8; i++) av[i] = (short)f2bf(xv[i]);
        *(short8*)&As[ar][ac0] = av;

        const short8* q = (const short8*)(WT + (size_t)bn * F_IN + k0 + bc0);
        *(short8*)&Bs[bn][bc0]     = q[0];
        *(short8*)&Bs[bn][bc0 + 8] = q[1];
        __syncthreads();

        short8 a[4], b[4];
        #pragma unroll
        for (int i = 0; i < 4; i++)
            a[i] = *(const short8*)&As[wm * 64 + i * 16 + l15][quad * 8];
        #pragma unroll
        for (int j = 0; j < 4; j++)
            b[j] = *(const short8*)&Bs[wn * 64 + j * 16 + l15][quad * 8];
        #pragma unroll
        for (int i = 0; i < 4; i++)
            #pragma unroll
            for (int j = 0; j < 4; j++)
                acc[i][j] = __builtin_amdgcn_mfma_f32_16x16x32_bf16(a[i], b[j], acc[i][j], 0, 0, 0);
        __syncthreads();
    }

    float asr[4], adr[4];
    #pragma unroll
    for (int j = 0; j < 4; j++) {
        asr[j] = a_s1[wn * HID + j * 16 + l15];
        adr[j] = a_d1[wn * HID + j * 16 + l15];
    }

    #pragma unroll
    for (int i = 0; i < 4; i++) {
        int rbase = m0 + wm * 64 + i * 16 + quad * 4;
        #pragma unroll
        for (int j = 0; j < 4; j++) {
            int col = wn * 64 + j * 16 + l15;
            #pragma unroll
            for (int r = 0; r < 4; r++) {
                int row = rbase + r;
                if (row < N_NODES) H[(size_t)row * C1 + col] = f2bf(acc[i][j][r]);
            }
        }
        #pragma unroll
        for (int r = 0; r < 4; r++) {
            int row = rbase + r;
            float s_ = acc[i][0][r] * asr[0] + acc[i][1][r] * asr[1]
                     + acc[i][2][r] * asr[2] + acc[i][3][r] * asr[3];
            float d_ = acc[i][0][r] * adr[0] + acc[i][1][r] * adr[1]
                     + acc[i][2][r] * adr[2] + acc[i][3][r] * adr[3];
            #pragma unroll
            for (int m = 8; m; m >>= 1) { s_ += __shfl_xor(s_, m); d_ += __shfl_xor(d_, m); }
            if (l15 == 0 && row < N_NODES) {
                AS[row * 4 + wn] = s_;
                AD[row * 4 + wn] = d_;
            }
        }
    }
}

// ========== place v3: LDS-resident bucket sort -> row_ptr + CSR E2.
//            Bucket base computed inline. [R10-verified] ==========
__global__ __launch_bounds__(512) void place_kernel(const int* __restrict__ bfill,
                                                    const int2* __restrict__ SB,
                                                    int* __restrict__ row_ptr,
                                                    int2* __restrict__ E2) {
    __shared__ int2 rec[RCAP];
    __shared__ int lh[BUK_NODES];     // histogram -> fill cursor
    __shared__ int excl[BUK_NODES];
    __shared__ int psum[512];
    const int b = blockIdx.x;
    const int n0 = b << BUK_SHIFT;
    const int t = threadIdx.x;

    // base_b = sum of clamped totals over buckets < b
    int v = 0;
    if (t < b) {
        #pragma unroll
        for (int r = 0; r < NREP; r++) {
            int c = bfill[(t * NREP + r) * BF_STRIDE];
            v += (c > SUBCAP) ? SUBCAP : c;
        }
    }
    psum[t] = v;
    __syncthreads();
    for (int s = 256; s > 0; s >>= 1) {
        if (t < s) psum[t] += psum[t + s];
        __syncthreads();
    }
    const int base_b = psum[0];

    int c[NREP], off[NREP];
    int tot = 0;
    #pragma unroll
    for (int r = 0; r < NREP; r++) {
        int cc = bfill[(b * NREP + r) * BF_STRIDE];
        c[r] = (cc > SUBCAP) ? SUBCAP : cc;
        off[r] = tot;
        tot += c[r];
    }
    if (t < BUK_NODES) lh[t] = 0;
    __syncthreads();
    #pragma unroll
    for (int r = 0; r < NREP; r++) {
        const int2* base = SB + (size_t)b * CAP + r * SUBCAP;
        for (int i = t; i < c[r]; i += 512) {
            int idx = off[r] + i;
            if (idx < RCAP) rec[idx] = base[i];
        }
    }
    if (tot > RCAP) tot = RCAP;
    __syncthreads();
    for (int i = t; i < tot; i += 512)
        atomicAdd(&lh[(((unsigned)rec[i].x) >> 16) - n0], 1);
    __syncthreads();
    if (t < BUK_NODES) excl[t] = lh[t];
    __syncthreads();
    #pragma unroll
    for (int s = 1; s < BUK_NODES; s <<= 1) {
        int u = (t < BUK_NODES && t >= s) ? excl[t - s] : 0;
        __syncthreads();
        if (t < BUK_NODES) excl[t] += u;
        __syncthreads();
    }
    if (t < BUK_NODES) {
        int e = excl[t] - lh[t];          // exclusive within bucket
        int node = n0 + t;
        if (node < N_NODES) row_ptr[node] = base_b + e;
        lh[t] = e;                        // reuse as fill cursor
    }
    __syncthreads();
    for (int i = t; i < tot; i += 512) {
        int2 v2 = rec[i];
        int d = (((unsigned)v2.x) >> 16) - n0;
        int pos = atomicAdd(&lh[d], 1);
        E2[base_b + pos] = make_int2(v2.x & 0xffff, v2.y);
    }
}

// ---- agg1 v5 (best measured: 65.5us, VGPR 28, 0 conflicts). [R10-verified] ----
__global__ __launch_bounds__(256) void agg1_csr_kernel(const int* __restrict__ row_ptr,
                                                       const int2* __restrict__ E2,
                                                       const float* __restrict__ AS,
                                                       const float* __restrict__ AD,
                                                       const unsigned short* __restrict__ H,
                                                       const float* __restrict__ b1,
                                                       unsigned short* __restrict__ OUT) {
    int n = blockIdx.x * 4 + (threadIdx.x >> 6);
    int lane = threadIdx.x & 63;
    if (n >= N_NODES) return;
    int l15 = lane & 15;
    int h = lane >> 4;
    int c0 = lane * 4;
    int beg = row_ptr[n];
    int end = (n + 1 < N_NODES) ? row_ptr[n + 1] : ET;
    float ad = AD[n * 4 + h];
    float den = 0.f;
    float a0 = 0.f, a1 = 0.f, a2 = 0.f, a3 = 0.f;

    for (int base = beg; base < end; base += 16) {
        int m = end - base; if (m > 16) m = 16;
        // phase 1: one exp per (edge, head)
        float pw = 0.f; int s = 0;
        if (l15 < m) {
            int2 e = E2[base + l15];
            s = e.x;
            float pe = __expf(leaky(AS[e.x * 4 + h] + ad));
            den += pe;
            pw = pe * __int_as_float(e.y);
        }
        // phase 2: gather + FMA
        int p = 0;
        for (; p + 4 <= m; p += 4) {
            int s0 = __shfl(s, p);
            int s1 = __shfl(s, p + 1);
            int s2 = __shfl(s, p + 2);
            int s3 = __shfl(s, p + 3);
            uint2 u0 = *(const uint2*)(H + (size_t)s0 * C1 + c0);
            uint2 u1 = *(const uint2*)(H + (size_t)s1 * C1 + c0);
            uint2 u2 = *(const uint2*)(H + (size_t)s2 * C1 + c0);
            uint2 u3 = *(const uint2*)(H + (size_t)s3 * C1 + c0);
            float w0 = __shfl(pw, h * 16 + p);
            float w1 = __shfl(pw, h * 16 + p + 1);
            float w2 = __shfl(pw, h * 16 + p + 2);
            float w3 = __shfl(pw, h * 16 + p + 3);
            a0 += w0 * bflo(u0.x) + w1 * bflo(u1.x) + w2 * bflo(u2.x) + w3 * bflo(u3.x);
            a1 += w0 * bfhi(u0.x) + w1 * bfhi(u1.x) + w2 * bfhi(u2.x) + w3 * bfhi(u3.x);
            a2 += w0 * bflo(u0.y) + w1 * bflo(u1.y) + w2 * bflo(u2.y) + w3 * bflo(u3.y);
            a3 += w0 * bfhi(u0.y) + w1 * bfhi(u1.y) + w2 * bfhi(u2.y) + w3 * bfhi(u3.y);
        }
        for (; p < m; p++) {
            int s0 = __shfl(s, p);
            uint2 u0 = *(const uint2*)(H + (size_t)s0 * C1 + c0);
            float w0 = __shfl(pw, h * 16 + p);
            a0 += w0 * bflo(u0.x);
            a1 += w0 * bfhi(u0.x);
            a2 += w0 * bflo(u0.y);
            a3 += w0 * bfhi(u0.y);
        }
    }
    // reduce den over the 16 lanes of this head group
    den += __shfl_xor(den, 1);
    den += __shfl_xor(den, 2);
    den += __shfl_xor(den, 4);
    den += __shfl_xor(den, 8);

    float r = 1.f / (den + 1e-16f);
    float4 bv = *(const float4*)(b1 + c0);
    float v0 = a0 * r + bv.x, v1 = a1 * r + bv.y, v2 = a2 * r + bv.z, v3 = a3 * r + bv.w;
    v0 = v0 > 0.f ? v0 : 0.f;
    v1 = v1 > 0.f ? v1 : 0.f;
    v2 = v2 > 0.f ? v2 : 0.f;
    v3 = v3 > 0.f ? v3 : 0.f;
    uint2 o;
    o.x = ((unsigned)f2bf(v1) << 16) | (unsigned)f2bf(v0);
    o.y = ((unsigned)f2bf(v3) << 16) | (unsigned)f2bf(v2);
    *(uint2*)(OUT + (size_t)n * C1 + c0) = o;
}

// ====== GEMM2 v2: 64-row tiles, 256 threads, 782 blocks (was 196 — sub-1
//        block/CU latency trap). Full-K A-tile staged upfront (8 loads in
//        flight, ONE barrier), then 8 K-steps of pure ds_read+MFMA. ======
#define BROW 264   /* LDS row stride: 528B, 16B-aligned */
__global__ __launch_bounds__(256) void gemm2_mfma_kernel(const unsigned short* __restrict__ A,
                                                         const float* __restrict__ W2,
                                                         const float* __restrict__ a_s2,
                                                         const float* __restrict__ a_d2,
                                                         unsigned short* __restrict__ H2b,
                                                         float* __restrict__ AS2,
                                                         float* __restrict__ AD2) {
    __shared__ short As[64][BROW];       // 33.8 KB (padded: 2-way bank alias, free)
    __shared__ short Bs[48 * BROW];      // 25.3 KB
    const int t = threadIdx.x;
    const int m0 = blockIdx.x * 64;
    const int lane = t & 63;
    const int wave = t >> 6;             // 0..3 -> 16-row frag each
    const int l15 = lane & 15;
    const int quad = lane >> 4;

    // stage A: thread t owns row ar, 64 contiguous elems; all 8 loads in flight
    const int ar = t >> 2;
    const int ac0 = (t & 3) * 64;
    short8 av[8];
    if (m0 + ar < N_NODES) {
        const short8* q = (const short8*)(A + (size_t)(m0 + ar) * C1 + ac0);
        #pragma unroll
        for (int i = 0; i < 8; i++) av[i] = q[i];
    } else {
        #pragma unroll
        for (int i = 0; i < 8; i++) av[i] = (short8){0,0,0,0,0,0,0,0};
    }
    // stage B (W2 is L2-hot after first blocks)
    for (int i = t; i < 48 * 256; i += 256) {
        int n = i >> 8, k = i & 255;
        float v = (n < NCLS) ? W2[k * NCLS + n] : 0.f;
        Bs[n * BROW + k] = (short)f2bf(v);
    }
    #pragma unroll
    for (int i = 0; i < 8; i++)
        *(short8*)&As[ar][ac0 + i * 8] = av[i];
    __syncthreads();

    floatx4 acc[3];
    #pragma unroll
    for (int j = 0; j < 3; j++) acc[j] = (floatx4){0.f, 0.f, 0.f, 0.f};

    #pragma unroll
    for (int k0 = 0; k0 < C1; k0 += 32) {
        short8 a = *(const short8*)&As[wave * 16 + l15][k0 + quad * 8];
        short8 b[3];
        #pragma unroll
        for (int j = 0; j < 3; j++)
            b[j] = *(const short8*)&Bs[(j * 16 + l15) * BROW + k0 + quad * 8];
        #pragma unroll
        for (int j = 0; j < 3; j++)
            acc[j] = __builtin_amdgcn_mfma_f32_16x16x32_bf16(a, b[j], acc[j], 0, 0, 0);
    }

    float asr[3], adr[3];
    #pragma unroll
    for (int j = 0; j < 3; j++) {
        int col = j * 16 + l15;
        asr[j] = (col < NCLS) ? a_s2[col] : 0.f;
        adr[j] = (col < NCLS) ? a_d2[col] : 0.f;
    }

    #pragma unroll
    for (int r = 0; r < 4; r++) {
        int row = m0 + wave * 16 + quad * 4 + r;
        float s_ = acc[0][r] * asr[0] + acc[1][r] * asr[1] + acc[2][r] * asr[2];
        float d_ = acc[0][r] * adr[0] + acc[1][r] * adr[1] + acc[2][r] * adr[2];
        #pragma unroll
        for (int m = 8; m; m >>= 1) { s_ += __shfl_xor(s_, m); d_ += __shfl_xor(d_, m); }
        if (l15 == 0 && row < N_NODES) { AS2[row] = s_; AD2[row] = d_; }
        #pragma unroll
        for (int j = 0; j < 3; j++) {
            int col = j * 16 + l15;
            if (col < NCLS && row < N_NODES)
                H2b[(size_t)row * NCLS + col] = f2bf(acc[j][r]);
        }
    }
}

// ---- agg2 v5: wave per node, 64-edge chunks, two-phase; single head ----
__global__ __launch_bounds__(256) void agg2_csr_kernel(const int* __restrict__ row_ptr,
                                                       const int2* __restrict__ E2,
                                                       const float* __restrict__ AS,
                                                       const float* __restrict__ AD,
                                                       const unsigned short* __restrict__ H2b,
                                                       const float* __restrict__ b2,
                                                       float* __restrict__ OUT) {
    int lane = threadIdx.x & 63;
    int n = blockIdx.x * 4 + (threadIdx.x >> 6);
    if (n >= N_NODES) return;
    int beg = row_ptr[n];
    int end = (n + 1 < N_NODES) ? row_ptr[n + 1] : ET;
    float ad = AD[n];
    bool act = lane < NCLS;
    float den = 0.f, acc = 0.f;

    for (int base = beg; base < end; base += 64) {
        int m = end - base; if (m > 64) m = 64;
        float pw = 0.f; int s = 0;
        if (lane < m) {
            int2 e = E2[base + lane];
            s = e.x;
            float pe = __expf(leaky(AS[e.x] + ad));
            den += pe;
            pw = pe * __int_as_float(e.y);
        }
        int p = 0;
        for (; p + 4 <= m; p += 4) {
            int s0 = __shfl(s, p);
            int s1 = __shfl(s, p + 1);
            int s2 = __shfl(s, p + 2);
            int s3 = __shfl(s, p + 3);
            float w0 = __shfl(pw, p);
            float w1 = __shfl(pw, p + 1);
            float w2 = __shfl(pw, p + 2);
            float w3 = __shfl(pw, p + 3);
            if (act) {
                float h0 = bf2f(H2b[(size_t)s0 * NCLS + lane]);
                float h1 = bf2f(H2b[(size_t)s1 * NCLS + lane]);
                float h2 = bf2f(H2b[(size_t)s2 * NCLS + lane]);
                float h3 = bf2f(H2b[(size_t)s3 * NCLS + lane]);
                acc += w0 * h0 + w1 * h1 + w2 * h2 + w3 * h3;
            }
        }
        for (; p < m; p++) {
            int s0 = __shfl(s, p);
            float w0 = __shfl(pw, p);
            if (act) acc += w0 * bf2f(H2b[(size_t)s0 * NCLS + lane]);
        }
    }
    den += __shfl_xor(den, 1);
    den += __shfl_xor(den, 2);
    den += __shfl_xor(den, 4);
    den += __shfl_xor(den, 8);
    den += __shfl_xor(den, 16);
    den += __shfl_xor(den, 32);
    if (act) {
        float r = 1.f / (den + 1e-16f);
        OUT[(size_t)n * NCLS + lane] = acc * r + b2[lane];
    }
}

extern "C" void kernel_launch(void* const* d_in, const int* in_sizes, int n_in,
                              void* d_out, int out_size, void* d_ws, size_t ws_size,
                              hipStream_t stream) {
    const float* x    = (const float*)d_in[0];
    const int*   ei   = (const int*)d_in[1];
    const float* ew   = (const float*)d_in[2];
    const float* W1   = (const float*)d_in[3];
    const float* a_s1 = (const float*)d_in[4];
    const float* a_d1 = (const float*)d_in[5];
    const float* b1   = (const float*)d_in[6];
    const float* W2   = (const float*)d_in[7];
    const float* a_s2 = (const float*)d_in[8];
    const float* a_d2 = (const float*)d_in[9];
    const float* b2   = (const float*)d_in[10];
    float* out = (float*)d_out;

    unsigned short* H1b  = (unsigned short*)d_ws;                      // 25.6 MB
    unsigned short* OUT1b = H1b + (size_t)N_NODES * C1;                // 25.6 MB
    float* AS1  = (float*)(OUT1b + (size_t)N_NODES * C1);
    float* AD1  = AS1 + N_NODES * HEADS;
    int* row_ptr = (int*)(AD1 + N_NODES * HEADS);
    int* bfill = row_ptr + N_NODES;        // NBUK*NREP*BF_STRIDE ints (zeroed in wt_prep)
    int2* E2  = (int2*)(bfill + NBUK * NREP * BF_STRIDE);              // 6.8 MB
    unsigned short* WT = (unsigned short*)(E2 + ET);                   // 0.26 MB
    int2* SB = (int2*)(WT + (size_t)F_IN * C1);                        // 12.8 MB (own region: passA runs with gemm1)
    unsigned short* H2b = H1b;             // alias (H1b dead before gemm2 writes)
    float* AS2  = (float*)(H2b + (size_t)N_NODES * NCLS);
    float* AD2  = AS2 + N_NODES;
    // total ~72 MB

    // ---- prep (wt_prep block(0,0) zeroes bfill; stream order covers passA) ----
    wt_prep_kernel<<<dim3(F_IN / 32, C1 / 32), dim3(32, 8), 0, stream>>>(W1, WT, bfill);

    // ---- fused gemm1 || passA ----
    g1pa_kernel<<<NG1 + NBLK_A, 512, 0, stream>>>(x, WT, a_s1, a_d1, H1b, AS1, AD1,
                                                  ei, ew, bfill, SB);

    // ---- CSR finish ----
    place_kernel<<<NBUK, 512, 0, stream>>>(bfill, SB, row_ptr, E2);

    // ---- layer 1 aggregate ----
    agg1_csr_kernel<<<(N_NODES + 3) / 4, 256, 0, stream>>>(row_ptr, E2, AS1, AD1, H1b, b1, OUT1b);

    // ---- layer 2 ----
    gemm2_mfma_kernel<<<(N_NODES + 63) / 64, 256, 0, stream>>>(OUT1b, W2, a_s2, a_d2, H2b, AS2, AD2);
    agg2_csr_kernel<<<(N_NODES + 3) / 4, 256, 0, stream>>>(row_ptr, E2, AS2, AD2, H2b, b2, out);
}

// Round 14
// 323.611 us; speedup vs baseline: 1.0319x; 1.0319x over previous
//
#include <hip/hip_runtime.h>
#include <math.h>

#define N_NODES 50000
#define N_EDGES 800000
#define ET (N_EDGES + N_NODES)   /* 850000 edges incl. self-loops */
#define F_IN 512
#define HID 64
#define HEADS 4
#define C1 (HEADS * HID)         /* 256 */
#define NCLS 40
#define NEG_SLOPE 0.2f

/* bucketed scatter params */
#define BUK_SHIFT 7
#define BUK_NODES (1 << BUK_SHIFT)                       /* 128 nodes per bucket */
#define NBUK ((N_NODES + BUK_NODES - 1) / BUK_NODES)    /* 391 */
#define CAP 4096           /* staging slots per bucket (mean load 2176) */
#define NREP 4             /* replicated append counters per bucket */
#define SUBCAP (CAP / NREP)  /* 1024 per sub-region (load ~544 +- 23) */
#define BF_STRIDE 8        /* ints between counters (32B) */
#define EPB_A 2048         /* edges per passA block */
#define NBLK_A ((ET + EPB_A - 1) / EPB_A)   /* 416 */
#define NG1 ((N_NODES + 127) / 128)         /* 391 gemm1 blocks */
#define RCAP 2560          /* place LDS record capacity (bucket mean 2176, +8 sigma) */

typedef __attribute__((ext_vector_type(8))) short short8;
typedef __attribute__((ext_vector_type(4))) float floatx4;

__device__ __forceinline__ float leaky(float x) { return fmaxf(x, NEG_SLOPE * x); }

// f32 -> bf16 round-to-nearest-even
__device__ __forceinline__ unsigned short f2bf(float f) {
    unsigned u = __float_as_uint(f);
    u += 0x7fffu + ((u >> 16) & 1u);
    return (unsigned short)(u >> 16);
}
__device__ __forceinline__ float bf2f(unsigned short u) {
    return __uint_as_float(((unsigned)u) << 16);
}
__device__ __forceinline__ float bflo(unsigned v) { return __uint_as_float(v << 16); }
__device__ __forceinline__ float bfhi(unsigned v) { return __uint_as_float(v & 0xffff0000u); }

__device__ __forceinline__ void edge_sd(int e, const int* __restrict__ ei,
                                        const float* __restrict__ ew,
                                        int& s, int& d, float& w) {
    if (e < N_EDGES) { s = ei[e]; d = ei[N_EDGES + e]; w = ew[e]; }
    else             { s = d = e - N_EDGES; w = 1.f; }
}

// ============ W1 -> bf16 transpose: WT[n][k] = bf16(W1[k][n]).
//              Block (0,0) zeroes bfill; block (1,0) builds W2T bf16 [48][256]
//              (zero-padded) so gemm2 can stage B with vector copies. ============
__global__ void wt_prep_kernel(const float* __restrict__ W, unsigned short* __restrict__ WT,
                               int* __restrict__ bfill,
                               const float* __restrict__ W2, unsigned short* __restrict__ W2T) {
    __shared__ float tile[32][33];
    int k0 = blockIdx.x * 32;
    int n0 = blockIdx.y * 32;
    int tx = threadIdx.x, ty = threadIdx.y;    // 32 x 8
    int tid = ty * 32 + tx;
    if (blockIdx.x == 0 && blockIdx.y == 0) {
        for (int i = tid; i < NBUK * NREP * BF_STRIDE; i += 256) bfill[i] = 0;
    }
    if (blockIdx.x == 1 && blockIdx.y == 0) {
        for (int i = tid; i < 48 * 256; i += 256) {
            int n = i >> 8, k = i & 255;
            float v = (n < NCLS) ? W2[k * NCLS + n] : 0.f;
            W2T[i] = f2bf(v);
        }
    }
    #pragma unroll
    for (int i = 0; i < 32; i += 8)
        tile[ty + i][tx] = W[(size_t)(k0 + ty + i) * C1 + n0 + tx];
    __syncthreads();
    #pragma unroll
    for (int i = 0; i < 32; i += 8)
        WT[(size_t)(n0 + ty + i) * F_IN + k0 + tx] = f2bf(tile[tx][ty + i]);
}

// ====== FUSED: gemm1 (blocks 0..NG1-1, R5-proven structure) ||
//        passA bucket multisplit (blocks NG1..). [R9/R10-verified] ======
__global__ __launch_bounds__(512) void g1pa_kernel(const float* __restrict__ X,
                                                   const unsigned short* __restrict__ WT,
                                                   const float* __restrict__ a_s1,
                                                   const float* __restrict__ a_d1,
                                                   unsigned short* __restrict__ H,
                                                   float* __restrict__ AS,
                                                   float* __restrict__ AD,
                                                   const int* __restrict__ ei,
                                                   const float* __restrict__ ew,
                                                   int* __restrict__ bfill,
                                                   int2* __restrict__ SB) {
    __shared__ short As[128][40];
    __shared__ short Bs[256][40];
    __shared__ int lcnt[NBUK];
    __shared__ int lbase[NBUK];
    const int t = threadIdx.x;

    if (blockIdx.x >= NG1) {
        // ---------------- passA path (512 threads, 2048 edges) ----------------
        const int pb = blockIdx.x - NG1;
        const int rep = pb & (NREP - 1);
        const int e0 = pb * EPB_A + t;
        for (int i = t; i < NBUK; i += 512) lcnt[i] = 0;
        __syncthreads();
        int rx[4], ry[4];
        #pragma unroll
        for (int i = 0; i < 4; i++) {
            int e = e0 + i * 512;
            rx[i] = -1;                   /* d<=49999 -> packed word never -1 */
            ry[i] = 0;
            if (e < ET) {
                int s, d; float w;
                edge_sd(e, ei, ew, s, d, w);
                rx[i] = s | (d << 16);
                ry[i] = __float_as_int(w);
                atomicAdd(&lcnt[d >> BUK_SHIFT], 1);
            }
        }
        __syncthreads();
        for (int i = t; i < NBUK; i += 512) {
            int c = lcnt[i];
            lbase[i] = c ? atomicAdd(&bfill[(i * NREP + rep) * BF_STRIDE], c) : 0;
            lcnt[i] = 0;
        }
        __syncthreads();
        #pragma unroll
        for (int i = 0; i < 4; i++) {
            if (rx[i] != -1) {
                int b = ((unsigned)rx[i] >> 16) >> BUK_SHIFT;
                int r = atomicAdd(&lcnt[b], 1);
                int idx = lbase[b] + r;
                if (idx < SUBCAP)   /* hard bound: never fault */
                    SB[(size_t)b * CAP + rep * SUBCAP + idx] = make_int2(rx[i], ry[i]);
            }
        }
        return;
    }

    // ---------------- gemm1 path (R5-proven 512-thread structure) ----------------
    const int m0 = blockIdx.x * 128;
    const int lane = t & 63;
    const int wave = t >> 6;
    const int wm = wave >> 2;
    const int wn = wave & 3;
    const int l15 = lane & 15;
    const int quad = lane >> 4;

    const int ar = t >> 2;
    const int ac0 = (t & 3) * 8;
    const int gr = m0 + ar;
    const int bn = t >> 1;
    const int bc0 = (t & 1) * 16;

    floatx4 acc[4][4];
    #pragma unroll
    for (int i = 0; i < 4; i++)
        #pragma unroll
        for (int j = 0; j < 4; j++) acc[i][j] = (floatx4){0.f, 0.f, 0.f, 0.f};

    for (int k0 = 0; k0 < F_IN; k0 += 32) {
        float xv[8];
        if (gr < N_NODES) {
            const float4* p = (const float4*)(X + (size_t)gr * F_IN + k0 + ac0);
            float4 v0 = p[0], v1 = p[1];
            xv[0] = v0.x; xv[1] = v0.y; xv[2] = v0.z; xv[3] = v0.w;
            xv[4] = v1.x; xv[5] = v1.y; xv[6] = v1.z; xv[7] = v1.w;
        } else {
            #pragma unroll
            for (int i = 0; i < 8; i++) xv[i] = 0.f;
        }
        short8 av;
        #pragma unroll
        for (int i = 0; i < 8; i++) av[i] = (short)f2bf(xv[i]);
        *(short8*)&As[ar][ac0] = av;

        const short8* q = (const short8*)(WT + (size_t)bn * F_IN + k0 + bc0);
        *(short8*)&Bs[bn][bc0]     = q[0];
        *(short8*)&Bs[bn][bc0 + 8] = q[1];
        __syncthreads();

        short8 a[4], b[4];
        #pragma unroll
        for (int i = 0; i < 4; i++)
            a[i] = *(const short8*)&As[wm * 64 + i * 16 + l15][quad * 8];
        #pragma unroll
        for (int j = 0; j < 4; j++)
            b[j] = *(const short8*)&Bs[wn * 64 + j * 16 + l15][quad * 8];
        #pragma unroll
        for (int i = 0; i < 4; i++)
            #pragma unroll
            for (int j = 0; j < 4; j++)
                acc[i][j] = __builtin_amdgcn_mfma_f32_16x16x32_bf16(a[i], b[j], acc[i][j], 0, 0, 0);
        __syncthreads();
    }

    float asr[4], adr[4];
    #pragma unroll
    for (int j = 0; j < 4; j++) {
        asr[j] = a_s1[wn * HID + j * 16 + l15];
        adr[j] = a_d1[wn * HID + j * 16 + l15];
    }

    #pragma unroll
    for (int i = 0; i < 4; i++) {
        int rbase = m0 + wm * 64 + i * 16 + quad * 4;
        #pragma unroll
        for (int j = 0; j < 4; j++) {
            int col = wn * 64 + j * 16 + l15;
            #pragma unroll
            for (int r = 0; r < 4; r++) {
                int row = rbase + r;
                if (row < N_NODES) H[(size_t)row * C1 + col] = f2bf(acc[i][j][r]);
            }
        }
        #pragma unroll
        for (int r = 0; r < 4; r++) {
            int row = rbase + r;
            float s_ = acc[i][0][r] * asr[0] + acc[i][1][r] * asr[1]
                     + acc[i][2][r] * asr[2] + acc[i][3][r] * asr[3];
            float d_ = acc[i][0][r] * adr[0] + acc[i][1][r] * adr[1]
                     + acc[i][2][r] * adr[2] + acc[i][3][r] * adr[3];
            #pragma unroll
            for (int m = 8; m; m >>= 1) { s_ += __shfl_xor(s_, m); d_ += __shfl_xor(d_, m); }
            if (l15 == 0 && row < N_NODES) {
                AS[row * 4 + wn] = s_;
                AD[row * 4 + wn] = d_;
            }
        }
    }
}

// ========== place v3: LDS-resident bucket sort -> row_ptr + CSR E2.
//            Bucket base computed inline. [R10-verified] ==========
__global__ __launch_bounds__(512) void place_kernel(const int* __restrict__ bfill,
                                                    const int2* __restrict__ SB,
                                                    int* __restrict__ row_ptr,
                                                    int2* __restrict__ E2) {
    __shared__ int2 rec[RCAP];
    __shared__ int lh[BUK_NODES];     // histogram -> fill cursor
    __shared__ int excl[BUK_NODES];
    __shared__ int psum[512];
    const int b = blockIdx.x;
    const int n0 = b << BUK_SHIFT;
    const int t = threadIdx.x;

    // base_b = sum of clamped totals over buckets < b
    int v = 0;
    if (t < b) {
        #pragma unroll
        for (int r = 0; r < NREP; r++) {
            int c = bfill[(t * NREP + r) * BF_STRIDE];
            v += (c > SUBCAP) ? SUBCAP : c;
        }
    }
    psum[t] = v;
    __syncthreads();
    for (int s = 256; s > 0; s >>= 1) {
        if (t < s) psum[t] += psum[t + s];
        __syncthreads();
    }
    const int base_b = psum[0];

    int c[NREP], off[NREP];
    int tot = 0;
    #pragma unroll
    for (int r = 0; r < NREP; r++) {
        int cc = bfill[(b * NREP + r) * BF_STRIDE];
        c[r] = (cc > SUBCAP) ? SUBCAP : cc;
        off[r] = tot;
        tot += c[r];
    }
    if (t < BUK_NODES) lh[t] = 0;
    __syncthreads();
    #pragma unroll
    for (int r = 0; r < NREP; r++) {
        const int2* base = SB + (size_t)b * CAP + r * SUBCAP;
        for (int i = t; i < c[r]; i += 512) {
            int idx = off[r] + i;
            if (idx < RCAP) rec[idx] = base[i];
        }
    }
    if (tot > RCAP) tot = RCAP;
    __syncthreads();
    for (int i = t; i < tot; i += 512)
        atomicAdd(&lh[(((unsigned)rec[i].x) >> 16) - n0], 1);
    __syncthreads();
    if (t < BUK_NODES) excl[t] = lh[t];
    __syncthreads();
    #pragma unroll
    for (int s = 1; s < BUK_NODES; s <<= 1) {
        int u = (t < BUK_NODES && t >= s) ? excl[t - s] : 0;
        __syncthreads();
        if (t < BUK_NODES) excl[t] += u;
        __syncthreads();
    }
    if (t < BUK_NODES) {
        int e = excl[t] - lh[t];          // exclusive within bucket
        int node = n0 + t;
        if (node < N_NODES) row_ptr[node] = base_b + e;
        lh[t] = e;                        // reuse as fill cursor
    }
    __syncthreads();
    for (int i = t; i < tot; i += 512) {
        int2 v2 = rec[i];
        int d = (((unsigned)v2.x) >> 16) - n0;
        int pos = atomicAdd(&lh[d], 1);
        E2[base_b + pos] = make_int2(v2.x & 0xffff, v2.y);
    }
}

// ---- agg1 v5 (best measured: 65.5us, VGPR 28, 0 conflicts). [R10-verified] ----
__global__ __launch_bounds__(256) void agg1_csr_kernel(const int* __restrict__ row_ptr,
                                                       const int2* __restrict__ E2,
                                                       const float* __restrict__ AS,
                                                       const float* __restrict__ AD,
                                                       const unsigned short* __restrict__ H,
                                                       const float* __restrict__ b1,
                                                       unsigned short* __restrict__ OUT) {
    int n = blockIdx.x * 4 + (threadIdx.x >> 6);
    int lane = threadIdx.x & 63;
    if (n >= N_NODES) return;
    int l15 = lane & 15;
    int h = lane >> 4;
    int c0 = lane * 4;
    int beg = row_ptr[n];
    int end = (n + 1 < N_NODES) ? row_ptr[n + 1] : ET;
    float ad = AD[n * 4 + h];
    float den = 0.f;
    float a0 = 0.f, a1 = 0.f, a2 = 0.f, a3 = 0.f;

    for (int base = beg; base < end; base += 16) {
        int m = end - base; if (m > 16) m = 16;
        // phase 1: one exp per (edge, head)
        float pw = 0.f; int s = 0;
        if (l15 < m) {
            int2 e = E2[base + l15];
            s = e.x;
            float pe = __expf(leaky(AS[e.x * 4 + h] + ad));
            den += pe;
            pw = pe * __int_as_float(e.y);
        }
        // phase 2: gather + FMA
        int p = 0;
        for (; p + 4 <= m; p += 4) {
            int s0 = __shfl(s, p);
            int s1 = __shfl(s, p + 1);
            int s2 = __shfl(s, p + 2);
            int s3 = __shfl(s, p + 3);
            uint2 u0 = *(const uint2*)(H + (size_t)s0 * C1 + c0);
            uint2 u1 = *(const uint2*)(H + (size_t)s1 * C1 + c0);
            uint2 u2 = *(const uint2*)(H + (size_t)s2 * C1 + c0);
            uint2 u3 = *(const uint2*)(H + (size_t)s3 * C1 + c0);
            float w0 = __shfl(pw, h * 16 + p);
            float w1 = __shfl(pw, h * 16 + p + 1);
            float w2 = __shfl(pw, h * 16 + p + 2);
            float w3 = __shfl(pw, h * 16 + p + 3);
            a0 += w0 * bflo(u0.x) + w1 * bflo(u1.x) + w2 * bflo(u2.x) + w3 * bflo(u3.x);
            a1 += w0 * bfhi(u0.x) + w1 * bfhi(u1.x) + w2 * bfhi(u2.x) + w3 * bfhi(u3.x);
            a2 += w0 * bflo(u0.y) + w1 * bflo(u1.y) + w2 * bflo(u2.y) + w3 * bflo(u3.y);
            a3 += w0 * bfhi(u0.y) + w1 * bfhi(u1.y) + w2 * bfhi(u2.y) + w3 * bfhi(u3.y);
        }
        for (; p < m; p++) {
            int s0 = __shfl(s, p);
            uint2 u0 = *(const uint2*)(H + (size_t)s0 * C1 + c0);
            float w0 = __shfl(pw, h * 16 + p);
            a0 += w0 * bflo(u0.x);
            a1 += w0 * bfhi(u0.x);
            a2 += w0 * bflo(u0.y);
            a3 += w0 * bfhi(u0.y);
        }
    }
    // reduce den over the 16 lanes of this head group
    den += __shfl_xor(den, 1);
    den += __shfl_xor(den, 2);
    den += __shfl_xor(den, 4);
    den += __shfl_xor(den, 8);

    float r = 1.f / (den + 1e-16f);
    float4 bv = *(const float4*)(b1 + c0);
    float v0 = a0 * r + bv.x, v1 = a1 * r + bv.y, v2 = a2 * r + bv.z, v3 = a3 * r + bv.w;
    v0 = v0 > 0.f ? v0 : 0.f;
    v1 = v1 > 0.f ? v1 : 0.f;
    v2 = v2 > 0.f ? v2 : 0.f;
    v3 = v3 > 0.f ? v3 : 0.f;
    uint2 o;
    o.x = ((unsigned)f2bf(v1) << 16) | (unsigned)f2bf(v0);
    o.y = ((unsigned)f2bf(v3) << 16) | (unsigned)f2bf(v2);
    *(uint2*)(OUT + (size_t)n * C1 + c0) = o;
}

// ====== GEMM2 v3: 64-row tiles, 782 blocks, full-K A-tile upfront + ONE
//        barrier (v2 skeleton), but B staged from precomputed bf16 W2T with
//        6 short8 vector copies/thread (v2's 48 scalar-load+convert rounds
//        were the R13 regression). ======
#define BROW 264   /* LDS row stride: 528B, 16B-aligned */
__global__ __launch_bounds__(256) void gemm2_mfma_kernel(const unsigned short* __restrict__ A,
                                                         const unsigned short* __restrict__ W2T,
                                                         const float* __restrict__ a_s2,
                                                         const float* __restrict__ a_d2,
                                                         unsigned short* __restrict__ H2b,
                                                         float* __restrict__ AS2,
                                                         float* __restrict__ AD2) {
    __shared__ short As[64][BROW];       // 33.8 KB (padded: 2-way bank alias, free)
    __shared__ short Bs[48 * BROW];      // 25.3 KB
    const int t = threadIdx.x;
    const int m0 = blockIdx.x * 64;
    const int lane = t & 63;
    const int wave = t >> 6;             // 0..3 -> 16-row frag each
    const int l15 = lane & 15;
    const int quad = lane >> 4;

    // stage A: thread t owns row ar, 64 contiguous elems; all 8 loads in flight
    const int ar = t >> 2;
    const int ac0 = (t & 3) * 64;
    short8 av[8];
    if (m0 + ar < N_NODES) {
        const short8* q = (const short8*)(A + (size_t)(m0 + ar) * C1 + ac0);
        #pragma unroll
        for (int i = 0; i < 8; i++) av[i] = q[i];
    } else {
        #pragma unroll
        for (int i = 0; i < 8; i++) av[i] = (short8){0,0,0,0,0,0,0,0};
    }
    // stage B: 6 vector copies/thread from bf16 W2T (L2-hot 24KB)
    #pragma unroll
    for (int i = 0; i < 6; i++) {
        int idx = (t + i * 256) * 8;          // element index, 8-aligned
        int n = idx >> 8, k = idx & 255;
        *(short8*)&Bs[n * BROW + k] = *(const short8*)(W2T + idx);
    }
    #pragma unroll
    for (int i = 0; i < 8; i++)
        *(short8*)&As[ar][ac0 + i * 8] = av[i];
    __syncthreads();

    floatx4 acc[3];
    #pragma unroll
    for (int j = 0; j < 3; j++) acc[j] = (floatx4){0.f, 0.f, 0.f, 0.f};

    #pragma unroll
    for (int k0 = 0; k0 < C1; k0 += 32) {
        short8 a = *(const short8*)&As[wave * 16 + l15][k0 + quad * 8];
        short8 b[3];
        #pragma unroll
        for (int j = 0; j < 3; j++)
            b[j] = *(const short8*)&Bs[(j * 16 + l15) * BROW + k0 + quad * 8];
        #pragma unroll
        for (int j = 0; j < 3; j++)
            acc[j] = __builtin_amdgcn_mfma_f32_16x16x32_bf16(a, b[j], acc[j], 0, 0, 0);
    }

    float asr[3], adr[3];
    #pragma unroll
    for (int j = 0; j < 3; j++) {
        int col = j * 16 + l15;
        asr[j] = (col < NCLS) ? a_s2[col] : 0.f;
        adr[j] = (col < NCLS) ? a_d2[col] : 0.f;
    }

    #pragma unroll
    for (int r = 0; r < 4; r++) {
        int row = m0 + wave * 16 + quad * 4 + r;
        float s_ = acc[0][r] * asr[0] + acc[1][r] * asr[1] + acc[2][r] * asr[2];
        float d_ = acc[0][r] * adr[0] + acc[1][r] * adr[1] + acc[2][r] * adr[2];
        #pragma unroll
        for (int m = 8; m; m >>= 1) { s_ += __shfl_xor(s_, m); d_ += __shfl_xor(d_, m); }
        if (l15 == 0 && row < N_NODES) { AS2[row] = s_; AD2[row] = d_; }
        #pragma unroll
        for (int j = 0; j < 3; j++) {
            int col = j * 16 + l15;
            if (col < NCLS && row < N_NODES)
                H2b[(size_t)row * NCLS + col] = f2bf(acc[j][r]);
        }
    }
}

// ---- agg2 v5: wave per node, 64-edge chunks, two-phase; single head ----
__global__ __launch_bounds__(256) void agg2_csr_kernel(const int* __restrict__ row_ptr,
                                                       const int2* __restrict__ E2,
                                                       const float* __restrict__ AS,
                                                       const float* __restrict__ AD,
                                                       const unsigned short* __restrict__ H2b,
                                                       const float* __restrict__ b2,
                                                       float* __restrict__ OUT) {
    int lane = threadIdx.x & 63;
    int n = blockIdx.x * 4 + (threadIdx.x >> 6);
    if (n >= N_NODES) return;
    int beg = row_ptr[n];
    int end = (n + 1 < N_NODES) ? row_ptr[n + 1] : ET;
    float ad = AD[n];
    bool act = lane < NCLS;
    float den = 0.f, acc = 0.f;

    for (int base = beg; base < end; base += 64) {
        int m = end - base; if (m > 64) m = 64;
        float pw = 0.f; int s = 0;
        if (lane < m) {
            int2 e = E2[base + lane];
            s = e.x;
            float pe = __expf(leaky(AS[e.x] + ad));
            den += pe;
            pw = pe * __int_as_float(e.y);
        }
        int p = 0;
        for (; p + 4 <= m; p += 4) {
            int s0 = __shfl(s, p);
            int s1 = __shfl(s, p + 1);
            int s2 = __shfl(s, p + 2);
            int s3 = __shfl(s, p + 3);
            float w0 = __shfl(pw, p);
            float w1 = __shfl(pw, p + 1);
            float w2 = __shfl(pw, p + 2);
            float w3 = __shfl(pw, p + 3);
            if (act) {
                float h0 = bf2f(H2b[(size_t)s0 * NCLS + lane]);
                float h1 = bf2f(H2b[(size_t)s1 * NCLS + lane]);
                float h2 = bf2f(H2b[(size_t)s2 * NCLS + lane]);
                float h3 = bf2f(H2b[(size_t)s3 * NCLS + lane]);
                acc += w0 * h0 + w1 * h1 + w2 * h2 + w3 * h3;
            }
        }
        for (; p < m; p++) {
            int s0 = __shfl(s, p);
            float w0 = __shfl(pw, p);
            if (act) acc += w0 * bf2f(H2b[(size_t)s0 * NCLS + lane]);
        }
    }
    den += __shfl_xor(den, 1);
    den += __shfl_xor(den, 2);
    den += __shfl_xor(den, 4);
    den += __shfl_xor(den, 8);
    den += __shfl_xor(den, 16);
    den += __shfl_xor(den, 32);
    if (act) {
        float r = 1.f / (den + 1e-16f);
        OUT[(size_t)n * NCLS + lane] = acc * r + b2[lane];
    }
}

extern "C" void kernel_launch(void* const* d_in, const int* in_sizes, int n_in,
                              void* d_out, int out_size, void* d_ws, size_t ws_size,
                              hipStream_t stream) {
    const float* x    = (const float*)d_in[0];
    const int*   ei   = (const int*)d_in[1];
    const float* ew   = (const float*)d_in[2];
    const float* W1   = (const float*)d_in[3];
    const float* a_s1 = (const float*)d_in[4];
    const float* a_d1 = (const float*)d_in[5];
    const float* b1   = (const float*)d_in[6];
    const float* W2   = (const float*)d_in[7];
    const float* a_s2 = (const float*)d_in[8];
    const float* a_d2 = (const float*)d_in[9];
    const float* b2   = (const float*)d_in[10];
    float* out = (float*)d_out;

    unsigned short* H1b  = (unsigned short*)d_ws;                      // 25.6 MB
    unsigned short* OUT1b = H1b + (size_t)N_NODES * C1;                // 25.6 MB
    float* AS1  = (float*)(OUT1b + (size_t)N_NODES * C1);
    float* AD1  = AS1 + N_NODES * HEADS;
    int* row_ptr = (int*)(AD1 + N_NODES * HEADS);
    int* bfill = row_ptr + N_NODES;        // NBUK*NREP*BF_STRIDE ints (zeroed in wt_prep)
    int2* E2  = (int2*)(bfill + NBUK * NREP * BF_STRIDE);              // 6.8 MB
    unsigned short* WT = (unsigned short*)(E2 + ET);                   // 0.26 MB
    unsigned short* W2T = WT + (size_t)F_IN * C1;                      // 24 KB bf16 [48][256]
    int2* SB = (int2*)(W2T + 48 * 256);                                // 12.8 MB
    unsigned short* H2b = H1b;             // alias (H1b dead before gemm2 writes)
    float* AS2  = (float*)(H2b + (size_t)N_NODES * NCLS);
    float* AD2  = AS2 + N_NODES;
    // total ~72 MB

    // ---- prep (block(0,0): bfill zero; block(1,0): W2T bf16) ----
    wt_prep_kernel<<<dim3(F_IN / 32, C1 / 32), dim3(32, 8), 0, stream>>>(W1, WT, bfill, W2, W2T);

    // ---- fused gemm1 || passA ----
    g1pa_kernel<<<NG1 + NBLK_A, 512, 0, stream>>>(x, WT, a_s1, a_d1, H1b, AS1, AD1,
                                                  ei, ew, bfill, SB);

    // ---- CSR finish ----
    place_kernel<<<NBUK, 512, 0, stream>>>(bfill, SB, row_ptr, E2);

    // ---- layer 1 aggregate ----
    agg1_csr_kernel<<<(N_NODES + 3) / 4, 256, 0, stream>>>(row_ptr, E2, AS1, AD1, H1b, b1, OUT1b);

    // ---- layer 2 ----
    gemm2_mfma_kernel<<<(N_NODES + 63) / 64, 256, 0, stream>>>(OUT1b, W2T, a_s2, a_d2, H2b, AS2, AD2);
    agg2_csr_kernel<<<(N_NODES + 3) / 4, 256, 0, stream>>>(row_ptr, E2, AS2, AD2, H2b, b2, out);
}

// Round 15
// 316.745 us; speedup vs baseline: 1.0542x; 1.0217x over previous
//
#include <hip/hip_runtime.h>
#include <math.h>

#define N_NODES 50000
#define N_EDGES 800000
#define ET (N_EDGES + N_NODES)   /* 850000 edges incl. self-loops */
#define F_IN 512
#define HID 64
#define HEADS 4
#define C1 (HEADS * HID)         /* 256 */
#define NCLS 40
#define NEG_SLOPE 0.2f

/* bucketed scatter params */
#define BUK_SHIFT 7
#define BUK_NODES (1 << BUK_SHIFT)                       /* 128 nodes per bucket */
#define NBUK ((N_NODES + BUK_NODES - 1) / BUK_NODES)    /* 391 */
#define CAP 4096           /* staging slots per bucket (mean load 2176) */
#define NREP 4             /* replicated append counters per bucket */
#define SUBCAP (CAP / NREP)  /* 1024 per sub-region (load ~544 +- 23) */
#define BF_STRIDE 8        /* ints between counters (32B) */
#define EPB_A 2048         /* edges per passA block */
#define NBLK_A ((ET + EPB_A - 1) / EPB_A)   /* 416 */
#define NG1 ((N_NODES + 127) / 128)         /* 391 gemm1 blocks */
#define RCAP 2560          /* place LDS record capacity (bucket mean 2176, +8 sigma) */

typedef __attribute__((ext_vector_type(8))) short short8;
typedef __attribute__((ext_vector_type(4))) float floatx4;

__device__ __forceinline__ float leaky(float x) { return fmaxf(x, NEG_SLOPE * x); }

// f32 -> bf16 round-to-nearest-even
__device__ __forceinline__ unsigned short f2bf(float f) {
    unsigned u = __float_as_uint(f);
    u += 0x7fffu + ((u >> 16) & 1u);
    return (unsigned short)(u >> 16);
}
__device__ __forceinline__ float bf2f(unsigned short u) {
    return __uint_as_float(((unsigned)u) << 16);
}
__device__ __forceinline__ float bflo(unsigned v) { return __uint_as_float(v << 16); }
__device__ __forceinline__ float bfhi(unsigned v) { return __uint_as_float(v & 0xffff0000u); }

__device__ __forceinline__ void edge_sd(int e, const int* __restrict__ ei,
                                        const float* __restrict__ ew,
                                        int& s, int& d, float& w) {
    if (e < N_EDGES) { s = ei[e]; d = ei[N_EDGES + e]; w = ew[e]; }
    else             { s = d = e - N_EDGES; w = 1.f; }
}

// ============ W1 -> bf16 transpose: WT[n][k] = bf16(W1[k][n]).
//              Block (0,0) also zeroes bfill (replaces hipMemsetAsync). ============
__global__ void wt_prep_kernel(const float* __restrict__ W, unsigned short* __restrict__ WT,
                               int* __restrict__ bfill) {
    __shared__ float tile[32][33];
    int k0 = blockIdx.x * 32;
    int n0 = blockIdx.y * 32;
    int tx = threadIdx.x, ty = threadIdx.y;    // 32 x 8
    if (blockIdx.x == 0 && blockIdx.y == 0) {
        int tid = ty * 32 + tx;
        for (int i = tid; i < NBUK * NREP * BF_STRIDE; i += 256) bfill[i] = 0;
    }
    #pragma unroll
    for (int i = 0; i < 32; i += 8)
        tile[ty + i][tx] = W[(size_t)(k0 + ty + i) * C1 + n0 + tx];
    __syncthreads();
    #pragma unroll
    for (int i = 0; i < 32; i += 8)
        WT[(size_t)(n0 + ty + i) * F_IN + k0 + tx] = f2bf(tile[tx][ty + i]);
}

// ====== FUSED: gemm1 (blocks 0..NG1-1, R5-proven structure) ||
//        passA bucket multisplit (blocks NG1..). [R9/R10-verified] ======
__global__ __launch_bounds__(512) void g1pa_kernel(const float* __restrict__ X,
                                                   const unsigned short* __restrict__ WT,
                                                   const float* __restrict__ a_s1,
                                                   const float* __restrict__ a_d1,
                                                   unsigned short* __restrict__ H,
                                                   float* __restrict__ AS,
                                                   float* __restrict__ AD,
                                                   const int* __restrict__ ei,
                                                   const float* __restrict__ ew,
                                                   int* __restrict__ bfill,
                                                   int2* __restrict__ SB) {
    __shared__ short As[128][40];
    __shared__ short Bs[256][40];
    __shared__ int lcnt[NBUK];
    __shared__ int lbase[NBUK];
    const int t = threadIdx.x;

    if (blockIdx.x >= NG1) {
        // ---------------- passA path (512 threads, 2048 edges) ----------------
        const int pb = blockIdx.x - NG1;
        const int rep = pb & (NREP - 1);
        const int e0 = pb * EPB_A + t;
        for (int i = t; i < NBUK; i += 512) lcnt[i] = 0;
        __syncthreads();
        int rx[4], ry[4];
        #pragma unroll
        for (int i = 0; i < 4; i++) {
            int e = e0 + i * 512;
            rx[i] = -1;                   /* d<=49999 -> packed word never -1 */
            ry[i] = 0;
            if (e < ET) {
                int s, d; float w;
                edge_sd(e, ei, ew, s, d, w);
                rx[i] = s | (d << 16);
                ry[i] = __float_as_int(w);
                atomicAdd(&lcnt[d >> BUK_SHIFT], 1);
            }
        }
        __syncthreads();
        for (int i = t; i < NBUK; i += 512) {
            int c = lcnt[i];
            lbase[i] = c ? atomicAdd(&bfill[(i * NREP + rep) * BF_STRIDE], c) : 0;
            lcnt[i] = 0;
        }
        __syncthreads();
        #pragma unroll
        for (int i = 0; i < 4; i++) {
            if (rx[i] != -1) {
                int b = ((unsigned)rx[i] >> 16) >> BUK_SHIFT;
                int r = atomicAdd(&lcnt[b], 1);
                int idx = lbase[b] + r;
                if (idx < SUBCAP)   /* hard bound: never fault */
                    SB[(size_t)b * CAP + rep * SUBCAP + idx] = make_int2(rx[i], ry[i]);
            }
        }
        return;
    }

    // ---------------- gemm1 path (R5-proven 512-thread structure) ----------------
    const int m0 = blockIdx.x * 128;
    const int lane = t & 63;
    const int wave = t >> 6;
    const int wm = wave >> 2;
    const int wn = wave & 3;
    const int l15 = lane & 15;
    const int quad = lane >> 4;

    const int ar = t >> 2;
    const int ac0 = (t & 3) * 8;
    const int gr = m0 + ar;
    const int bn = t >> 1;
    const int bc0 = (t & 1) * 16;

    floatx4 acc[4][4];
    #pragma unroll
    for (int i = 0; i < 4; i++)
        #pragma unroll
        for (int j = 0; j < 4; j++) acc[i][j] = (floatx4){0.f, 0.f, 0.f, 0.f};

    for (int k0 = 0; k0 < F_IN; k0 += 32) {
        float xv[8];
        if (gr < N_NODES) {
            const float4* p = (const float4*)(X + (size_t)gr * F_IN + k0 + ac0);
            float4 v0 = p[0], v1 = p[1];
            xv[0] = v0.x; xv[1] = v0.y; xv[2] = v0.z; xv[3] = v0.w;
            xv[4] = v1.x; xv[5] = v1.y; xv[6] = v1.z; xv[7] = v1.w;
        } else {
            #pragma unroll
            for (int i = 0; i < 8; i++) xv[i] = 0.f;
        }
        short8 av;
        #pragma unroll
        for (int i = 0; i < 8; i++) av[i] = (short)f2bf(xv[i]);
        *(short8*)&As[ar][ac0] = av;

        const short8* q = (const short8*)(WT + (size_t)bn * F_IN + k0 + bc0);
        *(short8*)&Bs[bn][bc0]     = q[0];
        *(short8*)&Bs[bn][bc0 + 8] = q[1];
        __syncthreads();

        short8 a[4], b[4];
        #pragma unroll
        for (int i = 0; i < 4; i++)
            a[i] = *(const short8*)&As[wm * 64 + i * 16 + l15][quad * 8];
        #pragma unroll
        for (int j = 0; j < 4; j++)
            b[j] = *(const short8*)&Bs[wn * 64 + j * 16 + l15][quad * 8];
        #pragma unroll
        for (int i = 0; i < 4; i++)
            #pragma unroll
            for (int j = 0; j < 4; j++)
                acc[i][j] = __builtin_amdgcn_mfma_f32_16x16x32_bf16(a[i], b[j], acc[i][j], 0, 0, 0);
        __syncthreads();
    }

    float asr[4], adr[4];
    #pragma unroll
    for (int j = 0; j < 4; j++) {
        asr[j] = a_s1[wn * HID + j * 16 + l15];
        adr[j] = a_d1[wn * HID + j * 16 + l15];
    }

    #pragma unroll
    for (int i = 0; i < 4; i++) {
        int rbase = m0 + wm * 64 + i * 16 + quad * 4;
        #pragma unroll
        for (int j = 0; j < 4; j++) {
            int col = wn * 64 + j * 16 + l15;
            #pragma unroll
            for (int r = 0; r < 4; r++) {
                int row = rbase + r;
                if (row < N_NODES) H[(size_t)row * C1 + col] = f2bf(acc[i][j][r]);
            }
        }
        #pragma unroll
        for (int r = 0; r < 4; r++) {
            int row = rbase + r;
            float s_ = acc[i][0][r] * asr[0] + acc[i][1][r] * asr[1]
                     + acc[i][2][r] * asr[2] + acc[i][3][r] * asr[3];
            float d_ = acc[i][0][r] * adr[0] + acc[i][1][r] * adr[1]
                     + acc[i][2][r] * adr[2] + acc[i][3][r] * adr[3];
            #pragma unroll
            for (int m = 8; m; m >>= 1) { s_ += __shfl_xor(s_, m); d_ += __shfl_xor(d_, m); }
            if (l15 == 0 && row < N_NODES) {
                AS[row * 4 + wn] = s_;
                AD[row * 4 + wn] = d_;
            }
        }
    }
}

// ========== place v3: LDS-resident bucket sort -> row_ptr + CSR E2.
//            Bucket base computed inline. [R10-verified] ==========
__global__ __launch_bounds__(512) void place_kernel(const int* __restrict__ bfill,
                                                    const int2* __restrict__ SB,
                                                    int* __restrict__ row_ptr,
                                                    int2* __restrict__ E2) {
    __shared__ int2 rec[RCAP];
    __shared__ int lh[BUK_NODES];     // histogram -> fill cursor
    __shared__ int excl[BUK_NODES];
    __shared__ int psum[512];
    const int b = blockIdx.x;
    const int n0 = b << BUK_SHIFT;
    const int t = threadIdx.x;

    // base_b = sum of clamped totals over buckets < b
    int v = 0;
    if (t < b) {
        #pragma unroll
        for (int r = 0; r < NREP; r++) {
            int c = bfill[(t * NREP + r) * BF_STRIDE];
            v += (c > SUBCAP) ? SUBCAP : c;
        }
    }
    psum[t] = v;
    __syncthreads();
    for (int s = 256; s > 0; s >>= 1) {
        if (t < s) psum[t] += psum[t + s];
        __syncthreads();
    }
    const int base_b = psum[0];

    int c[NREP], off[NREP];
    int tot = 0;
    #pragma unroll
    for (int r = 0; r < NREP; r++) {
        int cc = bfill[(b * NREP + r) * BF_STRIDE];
        c[r] = (cc > SUBCAP) ? SUBCAP : cc;
        off[r] = tot;
        tot += c[r];
    }
    if (t < BUK_NODES) lh[t] = 0;
    __syncthreads();
    #pragma unroll
    for (int r = 0; r < NREP; r++) {
        const int2* base = SB + (size_t)b * CAP + r * SUBCAP;
        for (int i = t; i < c[r]; i += 512) {
            int idx = off[r] + i;
            if (idx < RCAP) rec[idx] = base[i];
        }
    }
    if (tot > RCAP) tot = RCAP;
    __syncthreads();
    for (int i = t; i < tot; i += 512)
        atomicAdd(&lh[(((unsigned)rec[i].x) >> 16) - n0], 1);
    __syncthreads();
    if (t < BUK_NODES) excl[t] = lh[t];
    __syncthreads();
    #pragma unroll
    for (int s = 1; s < BUK_NODES; s <<= 1) {
        int u = (t < BUK_NODES && t >= s) ? excl[t - s] : 0;
        __syncthreads();
        if (t < BUK_NODES) excl[t] += u;
        __syncthreads();
    }
    if (t < BUK_NODES) {
        int e = excl[t] - lh[t];          // exclusive within bucket
        int node = n0 + t;
        if (node < N_NODES) row_ptr[node] = base_b + e;
        lh[t] = e;                        // reuse as fill cursor
    }
    __syncthreads();
    for (int i = t; i < tot; i += 512) {
        int2 v2 = rec[i];
        int d = (((unsigned)v2.x) >> 16) - n0;
        int pos = atomicAdd(&lh[d], 1);
        E2[base_b + pos] = make_int2(v2.x & 0xffff, v2.y);
    }
}

// ---- agg1 v5 (best measured: 65.5us, VGPR 28, 0 conflicts). [R10-verified] ----
__global__ __launch_bounds__(256) void agg1_csr_kernel(const int* __restrict__ row_ptr,
                                                       const int2* __restrict__ E2,
                                                       const float* __restrict__ AS,
                                                       const float* __restrict__ AD,
                                                       const unsigned short* __restrict__ H,
                                                       const float* __restrict__ b1,
                                                       unsigned short* __restrict__ OUT) {
    int n = blockIdx.x * 4 + (threadIdx.x >> 6);
    int lane = threadIdx.x & 63;
    if (n >= N_NODES) return;
    int l15 = lane & 15;
    int h = lane >> 4;
    int c0 = lane * 4;
    int beg = row_ptr[n];
    int end = (n + 1 < N_NODES) ? row_ptr[n + 1] : ET;
    float ad = AD[n * 4 + h];
    float den = 0.f;
    float a0 = 0.f, a1 = 0.f, a2 = 0.f, a3 = 0.f;

    for (int base = beg; base < end; base += 16) {
        int m = end - base; if (m > 16) m = 16;
        // phase 1: one exp per (edge, head)
        float pw = 0.f; int s = 0;
        if (l15 < m) {
            int2 e = E2[base + l15];
            s = e.x;
            float pe = __expf(leaky(AS[e.x * 4 + h] + ad));
            den += pe;
            pw = pe * __int_as_float(e.y);
        }
        // phase 2: gather + FMA
        int p = 0;
        for (; p + 4 <= m; p += 4) {
            int s0 = __shfl(s, p);
            int s1 = __shfl(s, p + 1);
            int s2 = __shfl(s, p + 2);
            int s3 = __shfl(s, p + 3);
            uint2 u0 = *(const uint2*)(H + (size_t)s0 * C1 + c0);
            uint2 u1 = *(const uint2*)(H + (size_t)s1 * C1 + c0);
            uint2 u2 = *(const uint2*)(H + (size_t)s2 * C1 + c0);
            uint2 u3 = *(const uint2*)(H + (size_t)s3 * C1 + c0);
            float w0 = __shfl(pw, h * 16 + p);
            float w1 = __shfl(pw, h * 16 + p + 1);
            float w2 = __shfl(pw, h * 16 + p + 2);
            float w3 = __shfl(pw, h * 16 + p + 3);
            a0 += w0 * bflo(u0.x) + w1 * bflo(u1.x) + w2 * bflo(u2.x) + w3 * bflo(u3.x);
            a1 += w0 * bfhi(u0.x) + w1 * bfhi(u1.x) + w2 * bfhi(u2.x) + w3 * bfhi(u3.x);
            a2 += w0 * bflo(u0.y) + w1 * bflo(u1.y) + w2 * bflo(u2.y) + w3 * bflo(u3.y);
            a3 += w0 * bfhi(u0.y) + w1 * bfhi(u1.y) + w2 * bfhi(u2.y) + w3 * bfhi(u3.y);
        }
        for (; p < m; p++) {
            int s0 = __shfl(s, p);
            uint2 u0 = *(const uint2*)(H + (size_t)s0 * C1 + c0);
            float w0 = __shfl(pw, h * 16 + p);
            a0 += w0 * bflo(u0.x);
            a1 += w0 * bfhi(u0.x);
            a2 += w0 * bflo(u0.y);
            a3 += w0 * bfhi(u0.y);
        }
    }
    // reduce den over the 16 lanes of this head group
    den += __shfl_xor(den, 1);
    den += __shfl_xor(den, 2);
    den += __shfl_xor(den, 4);
    den += __shfl_xor(den, 8);

    float r = 1.f / (den + 1e-16f);
    float4 bv = *(const float4*)(b1 + c0);
    float v0 = a0 * r + bv.x, v1 = a1 * r + bv.y, v2 = a2 * r + bv.z, v3 = a3 * r + bv.w;
    v0 = v0 > 0.f ? v0 : 0.f;
    v1 = v1 > 0.f ? v1 : 0.f;
    v2 = v2 > 0.f ? v2 : 0.f;
    v3 = v3 > 0.f ? v3 : 0.f;
    uint2 o;
    o.x = ((unsigned)f2bf(v1) << 16) | (unsigned)f2bf(v0);
    o.y = ((unsigned)f2bf(v3) << 16) | (unsigned)f2bf(v2);
    *(uint2*)(OUT + (size_t)n * C1 + c0) = o;
}

// ====== GEMM2 v1 (best measured): 256-row tiles, 512 threads, 196 blocks ======
#define BROW 264   /* LDS row stride for Bs2: 528B, 16B-aligned */
__global__ __launch_bounds__(512) void gemm2_mfma_kernel(const unsigned short* __restrict__ A,
                                                         const float* __restrict__ W2,
                                                         const float* __restrict__ a_s2,
                                                         const float* __restrict__ a_d2,
                                                         unsigned short* __restrict__ H2b,
                                                         float* __restrict__ AS2,
                                                         float* __restrict__ AD2) {
    __shared__ short As[256][40];        // 20 KB
    __shared__ short Bs[48 * BROW];      // 25.3 KB
    const int t = threadIdx.x;
    const int m0 = blockIdx.x * 256;
    const int lane = t & 63;
    const int wave = t >> 6;
    const int l15 = lane & 15;
    const int quad = lane >> 4;

    for (int i = t; i < 48 * 256; i += 512) {
        int n = i >> 8, k = i & 255;
        float v = (n < NCLS) ? W2[k * NCLS + n] : 0.f;
        Bs[n * BROW + k] = (short)f2bf(v);
    }

    const int ar = t >> 1;
    const int ac0 = (t & 1) * 16;

    floatx4 acc[2][3];
    #pragma unroll
    for (int i = 0; i < 2; i++)
        #pragma unroll
        for (int j = 0; j < 3; j++) acc[i][j] = (floatx4){0.f, 0.f, 0.f, 0.f};

    for (int k0 = 0; k0 < C1; k0 += 32) {
        const short8* q = (const short8*)(A + (size_t)(m0 + ar) * C1 + k0 + ac0);
        short8 v0 = q[0], v1 = q[1];
        __syncthreads();
        *(short8*)&As[ar][ac0]     = v0;
        *(short8*)&As[ar][ac0 + 8] = v1;
        __syncthreads();

        short8 a[2], b[3];
        #pragma unroll
        for (int i = 0; i < 2; i++)
            a[i] = *(const short8*)&As[wave * 32 + i * 16 + l15][quad * 8];
        #pragma unroll
        for (int j = 0; j < 3; j++)
            b[j] = *(const short8*)&Bs[(j * 16 + l15) * BROW + k0 + quad * 8];
        #pragma unroll
        for (int i = 0; i < 2; i++)
            #pragma unroll
            for (int j = 0; j < 3; j++)
                acc[i][j] = __builtin_amdgcn_mfma_f32_16x16x32_bf16(a[i], b[j], acc[i][j], 0, 0, 0);
    }

    float asr[3], adr[3];
    #pragma unroll
    for (int j = 0; j < 3; j++) {
        int col = j * 16 + l15;
        asr[j] = (col < NCLS) ? a_s2[col] : 0.f;
        adr[j] = (col < NCLS) ? a_d2[col] : 0.f;
    }

    #pragma unroll
    for (int i = 0; i < 2; i++) {
        #pragma unroll
        for (int r = 0; r < 4; r++) {
            int row = m0 + wave * 32 + i * 16 + quad * 4 + r;
            float s_ = acc[i][0][r] * asr[0] + acc[i][1][r] * asr[1] + acc[i][2][r] * asr[2];
            float d_ = acc[i][0][r] * adr[0] + acc[i][1][r] * adr[1] + acc[i][2][r] * adr[2];
            #pragma unroll
            for (int m = 8; m; m >>= 1) { s_ += __shfl_xor(s_, m); d_ += __shfl_xor(d_, m); }
            if (l15 == 0 && row < N_NODES) { AS2[row] = s_; AD2[row] = d_; }
            #pragma unroll
            for (int j = 0; j < 3; j++) {
                int col = j * 16 + l15;
                if (col < NCLS && row < N_NODES)
                    H2b[(size_t)row * NCLS + col] = f2bf(acc[i][j][r]);
            }
        }
    }
}

// ---- agg2 v5: wave per node, 64-edge chunks, two-phase; single head ----
__global__ __launch_bounds__(256) void agg2_csr_kernel(const int* __restrict__ row_ptr,
                                                       const int2* __restrict__ E2,
                                                       const float* __restrict__ AS,
                                                       const float* __restrict__ AD,
                                                       const unsigned short* __restrict__ H2b,
                                                       const float* __restrict__ b2,
                                                       float* __restrict__ OUT) {
    int lane = threadIdx.x & 63;
    int n = blockIdx.x * 4 + (threadIdx.x >> 6);
    if (n >= N_NODES) return;
    int beg = row_ptr[n];
    int end = (n + 1 < N_NODES) ? row_ptr[n + 1] : ET;
    float ad = AD[n];
    bool act = lane < NCLS;
    float den = 0.f, acc = 0.f;

    for (int base = beg; base < end; base += 64) {
        int m = end - base; if (m > 64) m = 64;
        float pw = 0.f; int s = 0;
        if (lane < m) {
            int2 e = E2[base + lane];
            s = e.x;
            float pe = __expf(leaky(AS[e.x] + ad));
            den += pe;
            pw = pe * __int_as_float(e.y);
        }
        int p = 0;
        for (; p + 4 <= m; p += 4) {
            int s0 = __shfl(s, p);
            int s1 = __shfl(s, p + 1);
            int s2 = __shfl(s, p + 2);
            int s3 = __shfl(s, p + 3);
            float w0 = __shfl(pw, p);
            float w1 = __shfl(pw, p + 1);
            float w2 = __shfl(pw, p + 2);
            float w3 = __shfl(pw, p + 3);
            if (act) {
                float h0 = bf2f(H2b[(size_t)s0 * NCLS + lane]);
                float h1 = bf2f(H2b[(size_t)s1 * NCLS + lane]);
                float h2 = bf2f(H2b[(size_t)s2 * NCLS + lane]);
                float h3 = bf2f(H2b[(size_t)s3 * NCLS + lane]);
                acc += w0 * h0 + w1 * h1 + w2 * h2 + w3 * h3;
            }
        }
        for (; p < m; p++) {
            int s0 = __shfl(s, p);
            float w0 = __shfl(pw, p);
            if (act) acc += w0 * bf2f(H2b[(size_t)s0 * NCLS + lane]);
        }
    }
    den += __shfl_xor(den, 1);
    den += __shfl_xor(den, 2);
    den += __shfl_xor(den, 4);
    den += __shfl_xor(den, 8);
    den += __shfl_xor(den, 16);
    den += __shfl_xor(den, 32);
    if (act) {
        float r = 1.f / (den + 1e-16f);
        OUT[(size_t)n * NCLS + lane] = acc * r + b2[lane];
    }
}

extern "C" void kernel_launch(void* const* d_in, const int* in_sizes, int n_in,
                              void* d_out, int out_size, void* d_ws, size_t ws_size,
                              hipStream_t stream) {
    const float* x    = (const float*)d_in[0];
    const int*   ei   = (const int*)d_in[1];
    const float* ew   = (const float*)d_in[2];
    const float* W1   = (const float*)d_in[3];
    const float* a_s1 = (const float*)d_in[4];
    const float* a_d1 = (const float*)d_in[5];
    const float* b1   = (const float*)d_in[6];
    const float* W2   = (const float*)d_in[7];
    const float* a_s2 = (const float*)d_in[8];
    const float* a_d2 = (const float*)d_in[9];
    const float* b2   = (const float*)d_in[10];
    float* out = (float*)d_out;

    unsigned short* H1b  = (unsigned short*)d_ws;                      // 25.6 MB
    unsigned short* OUT1b = H1b + (size_t)N_NODES * C1;                // 25.6 MB
    float* AS1  = (float*)(OUT1b + (size_t)N_NODES * C1);
    float* AD1  = AS1 + N_NODES * HEADS;
    int* row_ptr = (int*)(AD1 + N_NODES * HEADS);
    int* bfill = row_ptr + N_NODES;        // NBUK*NREP*BF_STRIDE ints (zeroed in wt_prep)
    int2* E2  = (int2*)(bfill + NBUK * NREP * BF_STRIDE);              // 6.8 MB
    unsigned short* WT = (unsigned short*)(E2 + ET);                   // 0.26 MB
    int2* SB = (int2*)(WT + (size_t)F_IN * C1);                        // 12.8 MB (own region: passA runs with gemm1)
    unsigned short* H2b = H1b;             // alias (H1b dead before gemm2 writes)
    float* AS2  = (float*)(H2b + (size_t)N_NODES * NCLS);
    float* AD2  = AS2 + N_NODES;
    // total ~72 MB

    // ---- prep (wt_prep block(0,0) zeroes bfill; stream order covers passA) ----
    wt_prep_kernel<<<dim3(F_IN / 32, C1 / 32), dim3(32, 8), 0, stream>>>(W1, WT, bfill);

    // ---- fused gemm1 || passA ----
    g1pa_kernel<<<NG1 + NBLK_A, 512, 0, stream>>>(x, WT, a_s1, a_d1, H1b, AS1, AD1,
                                                  ei, ew, bfill, SB);

    // ---- CSR finish ----
    place_kernel<<<NBUK, 512, 0, stream>>>(bfill, SB, row_ptr, E2);

    // ---- layer 1 aggregate ----
    agg1_csr_kernel<<<(N_NODES + 3) / 4, 256, 0, stream>>>(row_ptr, E2, AS1, AD1, H1b, b1, OUT1b);

    // ---- layer 2 ----
    gemm2_mfma_kernel<<<(N_NODES + 255) / 256, 512, 0, stream>>>(OUT1b, W2, a_s2, a_d2, H2b, AS2, AD2);
    agg2_csr_kernel<<<(N_NODES + 3) / 4, 256, 0, stream>>>(row_ptr, E2, AS2, AD2, H2b, b2, out);
}